// Round 3
// baseline (156.282 us; speedup 1.0000x reference)
//
#include <hip/hip_runtime.h>
#include <hip/hip_bf16.h>

#define CC   128
#define HH_  64
#define WW_  64
#define BB   8
#define HWSZ (HH_*WW_)      // 4096
#define CHW  (CC*HWSZ)      // 524288
#define BCHW (BB*CHW)       // 4194304
#define PAD  3
#define NP   49

typedef __attribute__((ext_vector_type(8))) short short8;
typedef __attribute__((ext_vector_type(4))) float float4v;

// ============ Kernel 0: W -> bf16 hi/lo split (into d_out scratch) ==========
__global__ __launch_bounds__(256) void prep_w(
    const float* __restrict__ Wq, const float* __restrict__ Wk,
    const float* __restrict__ Wv,
    unsigned short* __restrict__ whi, unsigned short* __restrict__ wlo)
{
    int i = blockIdx.x * 256 + threadIdx.x;          // 0..49151
    const float* src = (i < 16384) ? Wq : (i < 32768 ? Wk : Wv);
    float f = src[i & 16383];
    __hip_bfloat16 h = __float2bfloat16(f);
    float hf = __bfloat162float(h);
    __hip_bfloat16 l = __float2bfloat16(f - hf);
    unsigned short hu, lu;
    __builtin_memcpy(&hu, &h, 2);
    __builtin_memcpy(&lu, &l, 2);
    whi[i] = hu;
    wlo[i] = lu;
}

// ============ Kernel 1: q/k/v GEMM via split-bf16 MFMA ======================
// v6: xT column-block XOR swizzle. The old write pattern (lane-stride 4 rows
// x 136 shorts = 272 dwords = 16 mod 32 banks) put 32 lanes on 2 banks: a
// 16-way conflict on 128 b16 writes/thread. Swizzling the 16B column block
// by ((row>>3)&7) spreads lanes to 2/bank (free, m136) on both write & read.
__global__ __launch_bounds__(256, 2) void qkv_mfma(
    const float* __restrict__ x,
    const unsigned short* __restrict__ whi, const unsigned short* __restrict__ wlo,
    const float* __restrict__ bq, const float* __restrict__ bk,
    const float* __restrict__ bv, float* __restrict__ qkv)
{
    __shared__ unsigned short xT[2][128][136];   // [hi/lo][px][c swizzled]
    const int proj = blockIdx.y;
    const int n0g  = blockIdx.x << 7;
    const int b    = n0g >> 12;
    const int npx  = n0g & 4095;
    const int tid  = threadIdx.x;
    const int lane = tid & 63;
    const int wv   = tid >> 6;
    const int wm   = wv & 1, wn = wv >> 1;

    const float* xb = x + (size_t)b*CHW + npx;
    #pragma unroll
    for (int it = 0; it < 16; ++it) {
        int f  = tid + (it << 8);       // 0..4095
        int c  = f >> 5;                // 0..127
        int p4 = (f & 31) << 2;         // px quad
        // swizzled column: XOR 16B-block index (c>>3) with row-block (p4>>3)&7
        // ((p4+u)>>3 == p4>>3 for u in 0..3, p4 multiple of 4)
        int csw = (((c >> 3) ^ ((p4 >> 3) & 7)) << 3) | (c & 7);
        float4 v = *(const float4*)&xb[(size_t)c*HWSZ + p4];
        float vv[4] = {v.x, v.y, v.z, v.w};
        #pragma unroll
        for (int u = 0; u < 4; ++u) {
            __hip_bfloat16 h = __float2bfloat16(vv[u]);
            float hf = __bfloat162float(h);
            __hip_bfloat16 l = __float2bfloat16(vv[u] - hf);
            unsigned short hu, lu;
            __builtin_memcpy(&hu, &h, 2);
            __builtin_memcpy(&lu, &l, 2);
            xT[0][p4 + u][csw] = hu;
            xT[1][p4 + u][csw] = lu;
        }
    }

    const float* Bp = (proj == 0) ? bq : (proj == 1 ? bk : bv);
    const int q4 = lane >> 4;
    float4v acc[4][4];
    #pragma unroll
    for (int sm = 0; sm < 4; ++sm) {
        const int mb = wm*64 + sm*16 + q4*4;
        float4v bi;
        bi[0] = Bp[mb+0]; bi[1] = Bp[mb+1]; bi[2] = Bp[mb+2]; bi[3] = Bp[mb+3];
        #pragma unroll
        for (int sn = 0; sn < 4; ++sn) acc[sm][sn] = bi;
    }

    __syncthreads();

    const unsigned short* Wh = whi + (size_t)proj*16384;
    const unsigned short* Wl = wlo + (size_t)proj*16384;
    const int kq8  = q4 << 3;
    const int mrow = lane & 15;

    for (int pass = 0; pass < 3; ++pass) {
        const unsigned short* Wp = (pass == 2) ? Wl : Wh;
        const int xi = (pass == 1) ? 1 : 0;
        #pragma unroll
        for (int kc = 0; kc < 4; ++kc) {
            const int kb = kc << 5;
            short8 a[4], bf[4];
            #pragma unroll
            for (int sm = 0; sm < 4; ++sm) {
                const int m = wm*64 + sm*16 + mrow;
                a[sm] = *(const short8*)&Wp[(size_t)m*CC + kb + kq8];
            }
            #pragma unroll
            for (int sn = 0; sn < 4; ++sn) {
                const int n = wn*64 + sn*16 + mrow;
                const int scol = (kb + kq8) ^ (((n >> 3) & 7) << 3);
                bf[sn] = *(const short8*)&xT[xi][n][scol];
            }
            #pragma unroll
            for (int sm = 0; sm < 4; ++sm)
                #pragma unroll
                for (int sn = 0; sn < 4; ++sn)
                    acc[sm][sn] = __builtin_amdgcn_mfma_f32_16x16x32_bf16(
                        a[sm], bf[sn], acc[sm][sn], 0, 0, 0);
        }
    }

    float* op = qkv + (size_t)proj*BCHW + (size_t)b*CHW + npx;
    #pragma unroll
    for (int sm = 0; sm < 4; ++sm) {
        const int mb = wm*64 + sm*16 + q4*4;
        #pragma unroll
        for (int sn = 0; sn < 4; ++sn) {
            const int n = wn*64 + sn*16 + mrow;
            #pragma unroll
            for (int r = 0; r < 4; ++r)
                op[(size_t)(mb + r)*HWSZ + n] = acc[sm][sn][r];
        }
    }
}

// ================= Kernel 2: local attention v6 =============================
// Block = (b,h): 512 blocks x 512 thr (8 waves), 2 blocks/CU.
// Phase A unchanged. Phase C rewritten to be LDS-op lean:
//   v staged in the SAME [c=16][r=8][72] layout as k (identical float4
//   staging code; halo cols persist zeroed from phase A; slot r=7 = zeros).
//   Wave s owns chunk-channels {2s,2s+1}; lane (csub,q16): r in
//   {2csub,2csub+1}, px = w4..w4+3. Per (ch,r): 3x ds_read_b128 window
//   amortized over 4 px. Weights av[14] = raw e rows 14csub..14csub+13 in
//   regs (lg padded to 56 rows; rows 49..55 zeroed -> r=7 contributes 0).
//   12-shfl csub reduce; 1/den folded into the final coalesced float4 store.
__device__ __forceinline__ void load_chunk7(const float* __restrict__ src,
                                            int h, int c0, float4* stg) {
    const int tid = threadIdx.x;
    #pragma unroll
    for (int i = 0; i < 4; ++i) {
        int f   = tid + (i << 9);           // 0..2047 = 16ch * 8r * 16quads
        int c   = f >> 7;
        int rem = f & 127;
        int r   = rem >> 4;                 // 0..7 (row 7 unused -> zero)
        int q4  = (rem & 15) << 2;
        int hh  = h - PAD + r;
        if (r < 7 && (unsigned)hh < (unsigned)HH_)
            stg[i] = *(const float4*)&src[(size_t)(c0 + c)*HWSZ + hh*WW_ + q4];
        else
            stg[i] = make_float4(0.f, 0.f, 0.f, 0.f);
    }
}

__global__ __launch_bounds__(512, 4) void locatt(
    const float* __restrict__ qkv, float* __restrict__ out)
{
    __shared__ __align__(16) float smem[16*8*72];   // k-tile / v-tile, 36864 B
    __shared__ float lg[56][64];                    // 49 logit rows + 7 zero
    __shared__ float dn[64];

    const int blk = blockIdx.x;
    const int xs  = blk & 7;            // XCD
    const int jj  = blk >> 3;           // 0..63
    const int b   = jj >> 3;            // 0..7
    const int h   = (xs << 3) | (jj & 7);
    const int tid = threadIdx.x;
    const int s    = tid >> 6;          // wave 0..7
    const int lane = tid & 63;
    const int q16  = lane & 15;
    const int csub = lane >> 4;
    const int w4   = q16 << 2;

    const float* qp = qkv + (size_t)b*CHW;
    const float* kp = qkv + (size_t)BCHW + (size_t)b*CHW;
    const float* vp = qkv + (size_t)2*BCHW + (size_t)b*CHW;

    float (*ks)[8][72] = (float(*)[8][72])smem;

    // zero halo cols (0-3 & 68-71); staging only touches 4..67 -> persists
    // through BOTH phase A and phase C.
    if (tid < 256) {
        int idx = tid & 127;
        int c = idx >> 3, r = idx & 7;
        int col = (tid < 128) ? 0 : 68;
        *(float4*)&ks[c][r][col] = make_float4(0.f, 0.f, 0.f, 0.f);
    }

    const bool activeA = (s < 7);       // k-row slots 0..6

    float acc[7][4];
    #pragma unroll
    for (int dx = 0; dx < 7; ++dx)
        #pragma unroll
        for (int j = 0; j < 4; ++j) acc[dx][j] = 0.f;

    float4 stg[4];
    load_chunk7(kp, h, 0, stg);

    // -------- Phase A --------
    for (int ck = 0; ck < 8; ++ck) {
        #pragma unroll
        for (int i = 0; i < 4; ++i) {
            int f   = tid + (i << 9);
            int c   = f >> 7;
            int rem = f & 127;
            int r   = rem >> 4;
            int q4  = (rem & 15) << 2;
            *(float4*)&ks[c][r][4 + q4] = stg[i];
        }
        __syncthreads();
        if (ck < 7) load_chunk7(kp, h, (ck + 1) * 16, stg);

        if (activeA) {
            const int c0 = ck << 4;
            #pragma unroll
            for (int ci4 = 0; ci4 < 4; ++ci4) {
                const int c = (ci4 << 2) + csub;
                const float* qc = qp + (size_t)(c0 + c)*HWSZ
                                     + (size_t)h*WW_ + w4;
                float4 qv  = *(const float4*)qc;
                float4 ka  = *(const float4*)&ks[c][s][w4];
                float4 kb  = *(const float4*)&ks[c][s][w4 + 4];
                float4 kc2 = *(const float4*)&ks[c][s][w4 + 8];
                float kw[12] = {ka.x,ka.y,ka.z,ka.w, kb.x,kb.y,kb.z,kb.w,
                                kc2.x,kc2.y,kc2.z,kc2.w};
                float qa[4] = {qv.x,qv.y,qv.z,qv.w};
                #pragma unroll
                for (int dx = 0; dx < 7; ++dx)
                    #pragma unroll
                    for (int j = 0; j < 4; ++j) {
                        float kv = kw[j + dx + 1];   // spatial w4+j+dx-3
                        acc[dx][j] = fmaf(qa[j], kv, acc[dx][j]);
                    }
            }
        }
        __syncthreads();
    }

    // cross-csub reduce + lg write (active waves only)
    if (activeA) {
        #pragma unroll
        for (int dx = 0; dx < 7; ++dx)
            #pragma unroll
            for (int j = 0; j < 4; ++j) {
                acc[dx][j] += __shfl_xor(acc[dx][j], 16, 64);
                acc[dx][j] += __shfl_xor(acc[dx][j], 32, 64);
            }
        const int p0 = s * 7;
        #pragma unroll
        for (int dx = 0; dx < 7; ++dx) {
            if ((dx & 3) == csub)
                *(float4*)&lg[p0 + dx][w4] =
                    make_float4(acc[dx][0], acc[dx][1], acc[dx][2], acc[dx][3]);
        }
    }

    // prefetch v chunk 0 (same cooperative float4 pattern as k)
    load_chunk7(vp, h, 0, stg);
    __syncthreads();

    // -------- Phase B: softmax (OOB logits exactly 0, included) ------------
    if (tid < 64) {
        const int px = tid;
        float tv[NP];
        float m = -1e30f;
        #pragma unroll
        for (int p = 0; p < NP; ++p) { tv[p] = lg[p][px]; m = fmaxf(m, tv[p]); }
        float d = 0.f;
        #pragma unroll
        for (int p = 0; p < NP; ++p) {
            float e = __expf(tv[p] - m);
            d += e;
            lg[p][px] = e;
        }
        dn[px] = 1.f / d;
    } else {
        // zero lg rows 49..55 (7*64 = 448 floats; threads 64..511)
        int t = tid - 64;
        lg[49 + (t >> 6)][t & 63] = 0.f;
    }
    __syncthreads();

    // -------- Phase C --------
    // av[i] = e[p = 14*csub + i][w4..w4+3], i = 0..13 (p<=55; rows>=49 are 0)
    float4v av[14];
    #pragma unroll
    for (int i = 0; i < 14; ++i)
        av[i] = *(const float4v*)&lg[14*csub + i][w4];
    const float4 dnv = *(const float4*)&dn[w4];

    const int cA = s << 1, cB = (s << 1) + 1;
    for (int ck = 0; ck < 8; ++ck) {
        // store v chunk (identical layout/pattern as phase A k staging)
        #pragma unroll
        for (int i = 0; i < 4; ++i) {
            int f   = tid + (i << 9);
            int c   = f >> 7;
            int rem = f & 127;
            int r   = rem >> 4;
            int q4  = (rem & 15) << 2;
            *(float4*)&ks[c][r][4 + q4] = stg[i];
        }
        __syncthreads();
        if (ck < 7) load_chunk7(vp, h, (ck + 1) * 16, stg);

        float accA[4] = {0.f, 0.f, 0.f, 0.f};
        float accB[4] = {0.f, 0.f, 0.f, 0.f};
        #pragma unroll
        for (int rl = 0; rl < 2; ++rl) {
            const int r = (csub << 1) + rl;     // 0..7 (7 = zero slot)
            {   // channel cA
                float4 ka  = *(const float4*)&ks[cA][r][w4];
                float4 kb  = *(const float4*)&ks[cA][r][w4 + 4];
                float4 kc2 = *(const float4*)&ks[cA][r][w4 + 8];
                float vw[12] = {ka.x,ka.y,ka.z,ka.w, kb.x,kb.y,kb.z,kb.w,
                                kc2.x,kc2.y,kc2.z,kc2.w};
                #pragma unroll
                for (int dx = 0; dx < 7; ++dx)
                    #pragma unroll
                    for (int j = 0; j < 4; ++j)
                        accA[j] = fmaf(av[rl*7 + dx][j], vw[j + dx + 1], accA[j]);
            }
            {   // channel cB
                float4 ka  = *(const float4*)&ks[cB][r][w4];
                float4 kb  = *(const float4*)&ks[cB][r][w4 + 4];
                float4 kc2 = *(const float4*)&ks[cB][r][w4 + 8];
                float vw[12] = {ka.x,ka.y,ka.z,ka.w, kb.x,kb.y,kb.z,kb.w,
                                kc2.x,kc2.y,kc2.z,kc2.w};
                #pragma unroll
                for (int dx = 0; dx < 7; ++dx)
                    #pragma unroll
                    for (int j = 0; j < 4; ++j)
                        accB[j] = fmaf(av[rl*7 + dx][j], vw[j + dx + 1], accB[j]);
            }
        }
        // csub reduce: L1 xor32 both channels; L2 xor16 with channel-select
        // swap. Result: csub 0/2 -> cA total, csub 1/3 -> cB total.
        float fin[4];
        #pragma unroll
        for (int j = 0; j < 4; ++j) {
            accA[j] += __shfl_xor(accA[j], 32, 64);
            accB[j] += __shfl_xor(accB[j], 32, 64);
        }
        #pragma unroll
        for (int j = 0; j < 4; ++j) {
            float sel  = (csub & 1) ? accA[j] : accB[j];
            float oth  = __shfl_xor(sel, 16, 64);
            float mine = (csub & 1) ? accB[j] : accA[j];
            fin[j] = mine + oth;
        }
        if (csub < 2) {
            const int cg = (ck << 4) + ((s << 1) | csub);   // global channel
            float4 o = make_float4(fin[0]*dnv.x, fin[1]*dnv.y,
                                   fin[2]*dnv.z, fin[3]*dnv.w);
            *(float4*)&out[(size_t)b*CHW + (size_t)cg*HWSZ
                           + (size_t)h*WW_ + w4] = o;
        }
        __syncthreads();
    }
}

extern "C" void kernel_launch(void* const* d_in, const int* in_sizes, int n_in,
                              void* d_out, int out_size, void* d_ws, size_t ws_size,
                              hipStream_t stream) {
    const float* x  = (const float*)d_in[0];
    const float* Wq = (const float*)d_in[1];
    const float* bq = (const float*)d_in[2];
    const float* Wk = (const float*)d_in[3];
    const float* bk = (const float*)d_in[4];
    const float* Wv = (const float*)d_in[5];
    const float* bv = (const float*)d_in[6];
    float* out = (float*)d_out;
    float* qkv = (float*)d_ws;   // 3*BCHW*4 = 50.3 MB scratch

    // d_out doubles as scratch for bf16 W (196 KB); fully overwritten by
    // locatt afterwards (stream-ordered), safe under re-poisoning.
    unsigned short* whi = (unsigned short*)d_out;
    unsigned short* wlo = whi + 3*16384;

    prep_w  <<<192, 256, 0, stream>>>(Wq, Wk, Wv, whi, wlo);
    qkv_mfma<<<dim3(256, 3), 256, 0, stream>>>(x, whi, wlo, bq, bk, bv, qkv);
    locatt  <<<512, 512, 0, stream>>>(qkv, out);
}

// Round 4
// 153.460 us; speedup vs baseline: 1.0184x; 1.0184x over previous
//
#include <hip/hip_runtime.h>
#include <hip/hip_bf16.h>

#define CC   128
#define HH_  64
#define WW_  64
#define BB   8
#define HWSZ (HH_*WW_)      // 4096
#define CHW  (CC*HWSZ)      // 524288
#define BCHW (BB*CHW)       // 4194304
#define PAD  3
#define NP   49

typedef __attribute__((ext_vector_type(8))) short short8;
typedef __attribute__((ext_vector_type(4))) float float4v;

// async global->LDS 16B copy (source pre-swizzled, dest linear: m97/m173)
__device__ __forceinline__ void gload16(const unsigned short* g, unsigned short* l) {
    __builtin_amdgcn_global_load_lds(
        (const __attribute__((address_space(1))) void*)(g),
        (__attribute__((address_space(3))) void*)(l),
        16, 0, 0);
}

// ============ Kernel 0: W -> bf16 hi/lo split (into d_out scratch) ==========
__global__ __launch_bounds__(256) void prep_w(
    const float* __restrict__ Wq, const float* __restrict__ Wk,
    const float* __restrict__ Wv,
    unsigned short* __restrict__ whi, unsigned short* __restrict__ wlo)
{
    int i = blockIdx.x * 256 + threadIdx.x;          // 0..49151
    const float* src = (i < 16384) ? Wq : (i < 32768 ? Wk : Wv);
    float f = src[i & 16383];
    __hip_bfloat16 h = __float2bfloat16(f);
    float hf = __bfloat162float(h);
    __hip_bfloat16 l = __float2bfloat16(f - hf);
    unsigned short hu, lu;
    __builtin_memcpy(&hu, &h, 2);
    __builtin_memcpy(&lu, &l, 2);
    whi[i] = hu;
    wlo[i] = lu;
}

// ============ Kernel 0b: x -> bf16 hi/lo, transposed [b][px][c] =============
// Output rows are 128 bf16 (256 B); the 16B column block j holds logical
// c-block (j ^ (px&7)) -- the XOR swizzle is baked into the GLOBAL layout so
// qkv_mfma can stage with linear global_load_lds and un-XOR on the LDS read.
__global__ __launch_bounds__(256) void prep_x(
    const float* __restrict__ x, unsigned short* __restrict__ xhi,
    unsigned short* __restrict__ xlo)
{
    __shared__ float xt[128][132];     // [c][px], stride 132 (odd mod 32): 67584 B
    const int b   = blockIdx.x >> 5;
    const int p0  = (blockIdx.x & 31) << 7;
    const int tid = threadIdx.x;
    const float* xb = x + (size_t)b*CHW + p0;
    #pragma unroll
    for (int i = 0; i < 16; ++i) {
        int f  = tid + (i << 8);        // 0..4095
        int c  = f >> 5;
        int q4 = (f & 31) << 2;
        *(float4*)&xt[c][q4] = *(const float4*)&xb[(size_t)c*HWSZ + q4];
    }
    __syncthreads();
    const int px  = tid >> 1;           // 0..127 (local row)
    const int jb0 = (tid & 1) << 3;     // logical block base 0 / 8
    unsigned short* oh = xhi + (size_t)b*(size_t)(HWSZ*CC) + (size_t)(p0 + px)*CC;
    unsigned short* ol = xlo + (size_t)b*(size_t)(HWSZ*CC) + (size_t)(p0 + px)*CC;
    #pragma unroll
    for (int j = 0; j < 8; ++j) {
        int jb = jb0 + j;               // logical 16B block 0..15
        int pb = jb ^ (px & 7);         // physical block (XOR swizzle, bijective)
        unsigned short hs[8], ls[8];
        #pragma unroll
        for (int e = 0; e < 8; ++e) {
            float f = xt[jb*8 + e][px];
            __hip_bfloat16 h = __float2bfloat16(f);
            float hf = __bfloat162float(h);
            __hip_bfloat16 l = __float2bfloat16(f - hf);
            __builtin_memcpy(&hs[e], &h, 2);
            __builtin_memcpy(&ls[e], &l, 2);
        }
        *(short8*)&oh[pb << 3] = *(short8*)hs;
        *(short8*)&ol[pb << 3] = *(short8*)ls;
    }
}

// ============ Kernel 1: q/k/v GEMM via split-bf16 MFMA ======================
// v7: zero conversion work in the GEMM. x arrives pre-converted/pre-swizzled;
// staging is 16 async global_load_lds per thread (no VGPR roundtrip, no cvt).
__global__ __launch_bounds__(256, 2) void qkv_mfma(
    const unsigned short* __restrict__ xhi, const unsigned short* __restrict__ xlo,
    const unsigned short* __restrict__ whi, const unsigned short* __restrict__ wlo,
    const float* __restrict__ bq, const float* __restrict__ bk,
    const float* __restrict__ bv, float* __restrict__ qkv)
{
    __shared__ unsigned short xs[2][128][128];   // [hi/lo][px][c phys], 65536 B
    const int proj = blockIdx.y;
    const int n0g  = blockIdx.x << 7;
    const int b    = n0g >> 12;
    const int npx  = n0g & 4095;
    const int tid  = threadIdx.x;
    const int lane = tid & 63;
    const int wv   = tid >> 6;
    const int wm   = wv & 1, wn = wv >> 1;

    const unsigned short* xh = xhi + (size_t)b*(size_t)(HWSZ*CC) + (size_t)npx*CC;
    const unsigned short* xl = xlo + (size_t)b*(size_t)(HWSZ*CC) + (size_t)npx*CC;
    #pragma unroll
    for (int i = 0; i < 8; ++i) {
        int ch = (i << 8) + tid;        // 16B chunk id 0..2047 (linear both sides)
        gload16(xh + ch*8, &xs[0][0][0] + ch*8);
        gload16(xl + ch*8, &xs[1][0][0] + ch*8);
    }

    const float* Bp = (proj == 0) ? bq : (proj == 1 ? bk : bv);
    const int q4 = lane >> 4;
    float4v acc[4][4];
    #pragma unroll
    for (int sm = 0; sm < 4; ++sm) {
        const int mb = wm*64 + sm*16 + q4*4;
        float4v bi;
        bi[0] = Bp[mb+0]; bi[1] = Bp[mb+1]; bi[2] = Bp[mb+2]; bi[3] = Bp[mb+3];
        #pragma unroll
        for (int sn = 0; sn < 4; ++sn) acc[sm][sn] = bi;
    }

    __syncthreads();   // compiler drains vmcnt(0) before s_barrier (m97)

    const unsigned short* Wh = whi + (size_t)proj*16384;
    const unsigned short* Wl = wlo + (size_t)proj*16384;
    const int kq8  = q4 << 3;
    const int mrow = lane & 15;

    for (int pass = 0; pass < 3; ++pass) {
        const unsigned short* Wp = (pass == 2) ? Wl : Wh;
        const int xi = (pass == 1) ? 1 : 0;
        #pragma unroll
        for (int kc = 0; kc < 4; ++kc) {
            const int kb = kc << 5;
            short8 a[4], bf[4];
            #pragma unroll
            for (int sm = 0; sm < 4; ++sm) {
                const int m = wm*64 + sm*16 + mrow;
                a[sm] = *(const short8*)&Wp[(size_t)m*CC + kb + kq8];
            }
            #pragma unroll
            for (int sn = 0; sn < 4; ++sn) {
                const int n = wn*64 + sn*16 + mrow;
                const int pblk = ((kc << 2) | q4) ^ (mrow & 7);   // un-XOR
                bf[sn] = *(const short8*)&xs[xi][n][pblk << 3];
            }
            #pragma unroll
            for (int sm = 0; sm < 4; ++sm)
                #pragma unroll
                for (int sn = 0; sn < 4; ++sn)
                    acc[sm][sn] = __builtin_amdgcn_mfma_f32_16x16x32_bf16(
                        a[sm], bf[sn], acc[sm][sn], 0, 0, 0);
        }
    }

    float* op = qkv + (size_t)proj*BCHW + (size_t)b*CHW + npx;
    #pragma unroll
    for (int sm = 0; sm < 4; ++sm) {
        const int mb = wm*64 + sm*16 + q4*4;
        #pragma unroll
        for (int sn = 0; sn < 4; ++sn) {
            const int n = wn*64 + sn*16 + mrow;
            #pragma unroll
            for (int r = 0; r < 4; ++r)
                op[(size_t)(mb + r)*HWSZ + n] = acc[sm][sn][r];
        }
    }
}

// ================= Kernel 2: local attention v5 (reverted from v6) ==========
// Block = (b,h): 512 blocks x 512 thr (8 waves), 2 blocks/CU.
//   Phase A: wave s (s<7) handles k-row slot s; acc[7][4].
//   Phase C: wave s handles channel pair 2s; vT stride-17 layout (odd ->
//   conflict-free; v6's 72/64-stride layout tripled bank conflicts).
__device__ __forceinline__ void load_chunk7(const float* __restrict__ src,
                                            int h, int c0, float4* stg) {
    const int tid = threadIdx.x;
    #pragma unroll
    for (int i = 0; i < 4; ++i) {
        int f   = tid + (i << 9);           // 0..2047 = 16ch * 8r * 16quads
        int c   = f >> 7;
        int rem = f & 127;
        int r   = rem >> 4;                 // 0..7 (row 7 unused -> zero)
        int q4  = (rem & 15) << 2;
        int hh  = h - PAD + r;
        if (r < 7 && (unsigned)hh < (unsigned)HH_)
            stg[i] = *(const float4*)&src[(size_t)(c0 + c)*HWSZ + hh*WW_ + q4];
        else
            stg[i] = make_float4(0.f, 0.f, 0.f, 0.f);
    }
}

__global__ __launch_bounds__(512, 4) void locatt(
    const float* __restrict__ qkv, float* __restrict__ out)
{
    // union: phase A k-tile [16][8][72] (36864B) / phase C vT[7][72][17] (34272B)
    __shared__ __align__(16) float smem[16*8*72];   // 9216 floats
    __shared__ float lg[NP][64];                    // 12544 B
    __shared__ float dn[64];

    const int blk = blockIdx.x;
    const int xs  = blk & 7;            // XCD
    const int jj  = blk >> 3;           // 0..63
    const int b   = jj >> 3;            // 0..7
    const int h   = (xs << 3) | (jj & 7);
    const int tid = threadIdx.x;
    const int s    = tid >> 6;          // wave 0..7
    const int lane = tid & 63;
    const int q16  = lane & 15;
    const int csub = lane >> 4;
    const int w4   = q16 << 2;
    const int w    = lane;              // phase C pixel

    const float* qp = qkv + (size_t)b*CHW;
    const float* kp = qkv + (size_t)BCHW + (size_t)b*CHW;
    const float* vp = qkv + (size_t)2*BCHW + (size_t)b*CHW;

    float (*ks)[8][72] = (float(*)[8][72])smem;

    // zero k halo cols (cols 0-3 & 68-71; data stores touch 4..67 only)
    if (tid < 256) {
        int idx = tid & 127;
        int c = idx >> 3, r = idx & 7;
        int col = (tid < 128) ? 0 : 68;
        *(float4*)&ks[c][r][col] = make_float4(0.f, 0.f, 0.f, 0.f);
    }

    const bool activeA = (s < 7);       // k-row slots 0..6

    float acc[7][4];
    #pragma unroll
    for (int dx = 0; dx < 7; ++dx)
        #pragma unroll
        for (int j = 0; j < 4; ++j) acc[dx][j] = 0.f;

    float4 stg[4];
    load_chunk7(kp, h, 0, stg);

    // -------- Phase A --------
    for (int ck = 0; ck < 8; ++ck) {
        // store chunk (b128); r==7 writes zeros into unused slot 7
        #pragma unroll
        for (int i = 0; i < 4; ++i) {
            int f   = tid + (i << 9);
            int c   = f >> 7;
            int rem = f & 127;
            int r   = rem >> 4;
            int q4  = (rem & 15) << 2;
            *(float4*)&ks[c][r][4 + q4] = stg[i];
        }
        __syncthreads();
        if (ck < 7) load_chunk7(kp, h, (ck + 1) * 16, stg);

        if (activeA) {
            const int c0 = ck << 4;
            #pragma unroll
            for (int ci4 = 0; ci4 < 4; ++ci4) {
                const int c = (ci4 << 2) + csub;
                const float* qc = qp + (size_t)(c0 + c)*HWSZ
                                     + (size_t)h*WW_ + w4;
                float4 qv  = *(const float4*)qc;
                float4 ka  = *(const float4*)&ks[c][s][w4];
                float4 kb  = *(const float4*)&ks[c][s][w4 + 4];
                float4 kc2 = *(const float4*)&ks[c][s][w4 + 8];
                float kw[12] = {ka.x,ka.y,ka.z,ka.w, kb.x,kb.y,kb.z,kb.w,
                                kc2.x,kc2.y,kc2.z,kc2.w};
                float qa[4] = {qv.x,qv.y,qv.z,qv.w};
                #pragma unroll
                for (int dx = 0; dx < 7; ++dx)
                    #pragma unroll
                    for (int j = 0; j < 4; ++j) {
                        float kv = kw[j + dx + 1];   // spatial w4+j+dx-3
                        acc[dx][j] = fmaf(qa[j], kv, acc[dx][j]);
                    }
            }
        }
        __syncthreads();
    }

    // cross-csub reduce + lg write (active waves only)
    if (activeA) {
        #pragma unroll
        for (int dx = 0; dx < 7; ++dx)
            #pragma unroll
            for (int j = 0; j < 4; ++j) {
                acc[dx][j] += __shfl_xor(acc[dx][j], 16, 64);
                acc[dx][j] += __shfl_xor(acc[dx][j], 32, 64);
            }
        const int p0 = s * 7;
        #pragma unroll
        for (int dx = 0; dx < 7; ++dx) {
            if ((dx & 3) == csub)
                *(float4*)&lg[p0 + dx][w4] =
                    make_float4(acc[dx][0], acc[dx][1], acc[dx][2], acc[dx][3]);
        }
    }

    // prefetch v chunk 0: wave s -> channel pair cpl..cpl+1, rows 0..6
    const int cpl = s << 1;
    float vreg[14];
    {
        #pragma unroll
        for (int i = 0; i < 14; ++i) {
            int ch = (i >= 7) ? 1 : 0;
            int r  = i - 7*ch;
            int hh = h - PAD + r;
            vreg[i] = ((unsigned)hh < (unsigned)HH_)
                      ? vp[(size_t)(cpl + ch)*HWSZ + hh*WW_ + w] : 0.f;
        }
    }
    __syncthreads();

    // -------- Phase B: softmax (OOB logits exactly 0, included) ------------
    if (tid < 64) {
        const int px = tid;
        float tv[NP];
        float m = -1e30f;
        #pragma unroll
        for (int p = 0; p < NP; ++p) { tv[p] = lg[p][px]; m = fmaxf(m, tv[p]); }
        float d = 0.f;
        #pragma unroll
        for (int p = 0; p < NP; ++p) {
            float e = __expf(tv[p] - m);
            d += e;
            lg[p][px] = e;
        }
        dn[px] = 1.f / d;
    } else {
        // zero vT halo cols {0..3, 68..71} x 7r x 16 slots (896 floats)
        int t = tid - 64;
        for (int i = t; i < 896; i += 448) {
            int r    = i >> 7;
            int rem  = i & 127;
            int colg = rem >> 4;
            int col  = (colg < 4) ? colg : (64 + colg);
            smem[r*1224 + col*17 + (rem & 15)] = 0.f;
        }
    }
    __syncthreads();

    // -------- Phase C --------
    float a[NP];
    const float sc = dn[w];
    #pragma unroll
    for (int p = 0; p < NP; ++p) a[p] = lg[p][w] * sc;

    for (int ck = 0; ck < 8; ++ck) {
        // store vreg -> vT[r][4+w][c]  (stride 17 across lanes: conflict-free)
        #pragma unroll
        for (int i = 0; i < 14; ++i) {
            int ch = (i >= 7) ? 1 : 0;
            int r  = i - 7*ch;
            smem[r*1224 + (4 + w)*17 + cpl + ch] = vreg[i];
        }
        __syncthreads();
        if (ck < 7) {
            int c0v = (ck + 1) << 4;
            #pragma unroll
            for (int i = 0; i < 14; ++i) {
                int ch = (i >= 7) ? 1 : 0;
                int r  = i - 7*ch;
                int hh = h - PAD + r;
                vreg[i] = ((unsigned)hh < (unsigned)HH_)
                          ? vp[(size_t)(c0v + cpl + ch)*HWSZ + hh*WW_ + w] : 0.f;
            }
        }
        float ya = 0.f, yb = 0.f;
        #pragma unroll
        for (int r = 0; r < 7; ++r) {
            const float* vbase = &smem[r*1224 + (1 + w)*17 + cpl];
            #pragma unroll
            for (int dx = 0; dx < 7; ++dx) {
                float va = vbase[17*dx];       // channel cpl
                float vb = vbase[17*dx + 1];   // channel cpl+1 (ds_read2 pair)
                float aw = a[r*7 + dx];
                ya = fmaf(aw, va, ya);
                yb = fmaf(aw, vb, yb);
            }
        }
        float* op = out + (size_t)b*CHW + (size_t)(ck*16 + cpl)*HWSZ
                        + (size_t)h*WW_ + w;
        op[0]    = ya;   // c=cpl
        op[HWSZ] = yb;   // c=cpl+1
        __syncthreads();
    }
}

extern "C" void kernel_launch(void* const* d_in, const int* in_sizes, int n_in,
                              void* d_out, int out_size, void* d_ws, size_t ws_size,
                              hipStream_t stream) {
    const float* x  = (const float*)d_in[0];
    const float* Wq = (const float*)d_in[1];
    const float* bq = (const float*)d_in[2];
    const float* Wk = (const float*)d_in[3];
    const float* bk = (const float*)d_in[4];
    const float* Wv = (const float*)d_in[5];
    const float* bv = (const float*)d_in[6];
    float* out = (float*)d_out;
    float* qkv = (float*)d_ws;                    // 50.3 MB fp32 scratch

    // ws layout: [0, 50.3MB) qkv | [50.3, 58.7) xhi bf16 | [58.7, 67.1) xlo
    unsigned short* xhi = (unsigned short*)((char*)d_ws + (size_t)3*BCHW*4);
    unsigned short* xlo = xhi + (size_t)BCHW;

    // d_out doubles as scratch for bf16 W (196 KB); fully overwritten by
    // locatt afterwards (stream-ordered), safe under re-poisoning.
    unsigned short* whi = (unsigned short*)d_out;
    unsigned short* wlo = whi + 3*16384;

    prep_w  <<<192, 256, 0, stream>>>(Wq, Wk, Wv, whi, wlo);
    prep_x  <<<256, 256, 0, stream>>>(x, xhi, xlo);
    qkv_mfma<<<dim3(256, 3), 256, 0, stream>>>(xhi, xlo, whi, wlo, bq, bk, bv, qkv);
    locatt  <<<512, 512, 0, stream>>>(qkv, out);
}

// Round 5
// 136.717 us; speedup vs baseline: 1.1431x; 1.1225x over previous
//
#include <hip/hip_runtime.h>
#include <hip/hip_bf16.h>

#define CC   128
#define HH_  64
#define WW_  64
#define BB   8
#define HWSZ (HH_*WW_)      // 4096
#define CHW  (CC*HWSZ)      // 524288
#define BCHW (BB*CHW)       // 4194304
#define PAD  3
#define NP   49

typedef __attribute__((ext_vector_type(8))) short short8;
typedef __attribute__((ext_vector_type(4))) float float4v;

// ============ Kernel 0: W -> bf16 hi/lo split (into d_out scratch) ==========
__global__ __launch_bounds__(256) void prep_w(
    const float* __restrict__ Wq, const float* __restrict__ Wk,
    const float* __restrict__ Wv,
    unsigned short* __restrict__ whi, unsigned short* __restrict__ wlo)
{
    int i = blockIdx.x * 256 + threadIdx.x;          // 0..49151
    const float* src = (i < 16384) ? Wq : (i < 32768 ? Wk : Wv);
    float f = src[i & 16383];
    __hip_bfloat16 h = __float2bfloat16(f);
    float hf = __bfloat162float(h);
    __hip_bfloat16 l = __float2bfloat16(f - hf);
    unsigned short hu, lu;
    __builtin_memcpy(&hu, &h, 2);
    __builtin_memcpy(&lu, &l, 2);
    whi[i] = hu;
    wlo[i] = lu;
}

// ============ Kernel 1: q/k/v GEMM via split-bf16 MFMA (R2 version) =========
// xT column-block XOR swizzle: breaks the 16-way write conflict of the
// unswizzled layout (lane stride 272 dwords = 16 mod 32 banks).
__global__ __launch_bounds__(256, 2) void qkv_mfma(
    const float* __restrict__ x,
    const unsigned short* __restrict__ whi, const unsigned short* __restrict__ wlo,
    const float* __restrict__ bq, const float* __restrict__ bk,
    const float* __restrict__ bv, float* __restrict__ qkv)
{
    __shared__ unsigned short xT[2][128][136];   // [hi/lo][px][c swizzled]
    const int proj = blockIdx.y;
    const int n0g  = blockIdx.x << 7;
    const int b    = n0g >> 12;
    const int npx  = n0g & 4095;
    const int tid  = threadIdx.x;
    const int lane = tid & 63;
    const int wv   = tid >> 6;
    const int wm   = wv & 1, wn = wv >> 1;

    const float* xb = x + (size_t)b*CHW + npx;
    #pragma unroll
    for (int it = 0; it < 16; ++it) {
        int f  = tid + (it << 8);       // 0..4095
        int c  = f >> 5;                // 0..127
        int p4 = (f & 31) << 2;         // px quad
        int csw = (((c >> 3) ^ ((p4 >> 3) & 7)) << 3) | (c & 7);
        float4 v = *(const float4*)&xb[(size_t)c*HWSZ + p4];
        float vv[4] = {v.x, v.y, v.z, v.w};
        #pragma unroll
        for (int u = 0; u < 4; ++u) {
            __hip_bfloat16 h = __float2bfloat16(vv[u]);
            float hf = __bfloat162float(h);
            __hip_bfloat16 l = __float2bfloat16(vv[u] - hf);
            unsigned short hu, lu;
            __builtin_memcpy(&hu, &h, 2);
            __builtin_memcpy(&lu, &l, 2);
            xT[0][p4 + u][csw] = hu;
            xT[1][p4 + u][csw] = lu;
        }
    }

    const float* Bp = (proj == 0) ? bq : (proj == 1 ? bk : bv);
    const int q4 = lane >> 4;
    float4v acc[4][4];
    #pragma unroll
    for (int sm = 0; sm < 4; ++sm) {
        const int mb = wm*64 + sm*16 + q4*4;
        float4v bi;
        bi[0] = Bp[mb+0]; bi[1] = Bp[mb+1]; bi[2] = Bp[mb+2]; bi[3] = Bp[mb+3];
        #pragma unroll
        for (int sn = 0; sn < 4; ++sn) acc[sm][sn] = bi;
    }

    __syncthreads();

    const unsigned short* Wh = whi + (size_t)proj*16384;
    const unsigned short* Wl = wlo + (size_t)proj*16384;
    const int kq8  = q4 << 3;
    const int mrow = lane & 15;

    for (int pass = 0; pass < 3; ++pass) {
        const unsigned short* Wp = (pass == 2) ? Wl : Wh;
        const int xi = (pass == 1) ? 1 : 0;
        #pragma unroll
        for (int kc = 0; kc < 4; ++kc) {
            const int kb = kc << 5;
            short8 a[4], bf[4];
            #pragma unroll
            for (int sm = 0; sm < 4; ++sm) {
                const int m = wm*64 + sm*16 + mrow;
                a[sm] = *(const short8*)&Wp[(size_t)m*CC + kb + kq8];
            }
            #pragma unroll
            for (int sn = 0; sn < 4; ++sn) {
                const int n = wn*64 + sn*16 + mrow;
                const int scol = (kb + kq8) ^ (((n >> 3) & 7) << 3);
                bf[sn] = *(const short8*)&xT[xi][n][scol];
            }
            #pragma unroll
            for (int sm = 0; sm < 4; ++sm)
                #pragma unroll
                for (int sn = 0; sn < 4; ++sn)
                    acc[sm][sn] = __builtin_amdgcn_mfma_f32_16x16x32_bf16(
                        a[sm], bf[sn], acc[sm][sn], 0, 0, 0);
        }
    }

    float* op = qkv + (size_t)proj*BCHW + (size_t)b*CHW + npx;
    #pragma unroll
    for (int sm = 0; sm < 4; ++sm) {
        const int mb = wm*64 + sm*16 + q4*4;
        #pragma unroll
        for (int sn = 0; sn < 4; ++sn) {
            const int n = wn*64 + sn*16 + mrow;
            #pragma unroll
            for (int r = 0; r < 4; ++r)
                op[(size_t)(mb + r)*HWSZ + n] = acc[sm][sn][r];
        }
    }
}

// ================= Kernel 2: local attention v8 = v3 + LDS double-buffer ====
// Block = (b, h0..h0+1), 512 thr (8 waves), grid 256 (1 block/CU).
// v3's partition (best measured: ~44us) with double-buffered tiles in both
// phases: the chunk-(ck+1) store targets the buffer not being read, so the
// trailing barrier per chunk is deleted -> 18 barriers instead of 33. Each
// global prefetch is issued right after the barrier and drained one full
// compute phase later. FMA order identical to v3 (bitwise-same outputs).
// LDS: smem 2x9792 floats (A uses 9216/buf, C uses 9792/buf) + lg + dn
//    = 78336 + 25088 + 512 = 103936 B (1 block/CU; >64KB static LDS is
//    proven on this toolchain by the 67.6KB prep_x that ran in R4).
__device__ __forceinline__ void load_chunk8(const float* __restrict__ src,
                                            int h0, int c0, float4* stg) {
    const int tid = threadIdx.x;
    #pragma unroll
    for (int i = 0; i < 4; ++i) {
        int f   = tid + (i << 9);           // 0..2047 = 16ch * 8r * 16quads
        int c   = f >> 7;
        int rem = f & 127;
        int r   = rem >> 4;
        int q4  = (rem & 15) << 2;
        int hh  = h0 - PAD + r;
        if ((unsigned)hh < (unsigned)HH_)
            stg[i] = *(const float4*)&src[(size_t)(c0 + c)*HWSZ + hh*WW_ + q4];
        else
            stg[i] = make_float4(0.f, 0.f, 0.f, 0.f);
    }
}

__global__ __launch_bounds__(512) void locatt(
    const float* __restrict__ qkv, float* __restrict__ out)
{
    __shared__ __align__(16) float smem[2*9792];    // A: +0/+9216, C: +0/+9792
    __shared__ float lg[2][NP][64];                 // 25088 B
    __shared__ float dn[2][64];

    const int blk = blockIdx.x;
    const int xs  = blk & 7;
    const int jj  = blk >> 3;
    const int b   = jj >> 2;
    const int h0  = (((xs << 2) | (jj & 3)) << 1);
    const int tid = threadIdx.x;
    const int s   = tid >> 6;      // wave 0..7
    const int lane = tid & 63;
    const int q16  = lane & 15;
    const int csub = lane >> 4;
    const int w4   = q16 << 2;
    const int w    = lane;         // phase C pixel

    const float* qp = qkv + (size_t)b*CHW;
    const float* kp = qkv + (size_t)BCHW + (size_t)b*CHW;
    const float* vp = qkv + (size_t)2*BCHW + (size_t)b*CHW;

    // zero k halo cols (0-3 & 68-71) in BOTH A-buffers; staging writes only
    // cols 4..67, so halos persist for all of phase A.
    {
        int buf = tid >> 8;                 // 0..1
        int t2  = tid & 255;
        int idx = t2 & 127;
        int c = idx >> 3, r = idx & 7;
        int col = (t2 < 128) ? 0 : 68;
        *(float4*)&smem[buf*9216 + (c*8 + r)*72 + col] =
            make_float4(0.f, 0.f, 0.f, 0.f);
    }

    const bool do0 = (s < 7);   // k-row s serves row0 p = s*7+dx
    const bool do1 = (s >= 1);  // and row1 p = (s-1)*7+dx

    float acc0[7][4], acc1[7][4];
    #pragma unroll
    for (int dx = 0; dx < 7; ++dx)
        #pragma unroll
        for (int j = 0; j < 4; ++j) { acc0[dx][j] = 0.f; acc1[dx][j] = 0.f; }

    float4 stg[4];
    load_chunk8(kp, h0, 0, stg);

    // -------- Phase A (double-buffered, 1 barrier/chunk) --------
    for (int ck = 0; ck < 8; ++ck) {
        float* ksb = smem + (ck & 1)*9216;      // [16][8][72]
        #pragma unroll
        for (int i = 0; i < 4; ++i) {
            int f   = tid + (i << 9);
            int c   = f >> 7;
            int rem = f & 127;
            int r   = rem >> 4;
            int q4  = (rem & 15) << 2;
            *(float4*)&ksb[(c*8 + r)*72 + 4 + q4] = stg[i];
        }
        __syncthreads();
        if (ck < 7) load_chunk8(kp, h0, (ck + 1) * 16, stg);

        const int c0 = ck << 4;
        #pragma unroll
        for (int ci4 = 0; ci4 < 4; ++ci4) {
            const int c = (ci4 << 2) + csub;
            const float* qc = qp + (size_t)(c0 + c)*HWSZ + h0*WW_ + w4;
            float4 q0v = do0 ? *(const float4*)qc
                             : make_float4(0.f, 0.f, 0.f, 0.f);
            float4 q1v = do1 ? *(const float4*)(qc + WW_)
                             : make_float4(0.f, 0.f, 0.f, 0.f);
            const float* krow = &ksb[(c*8 + s)*72];
            float4 ka  = *(const float4*)&krow[w4];
            float4 kb  = *(const float4*)&krow[w4 + 4];
            float4 kc2 = *(const float4*)&krow[w4 + 8];
            float kw[12] = {ka.x,ka.y,ka.z,ka.w, kb.x,kb.y,kb.z,kb.w,
                            kc2.x,kc2.y,kc2.z,kc2.w};
            float q0a[4] = {q0v.x,q0v.y,q0v.z,q0v.w};
            float q1a[4] = {q1v.x,q1v.y,q1v.z,q1v.w};
            #pragma unroll
            for (int dx = 0; dx < 7; ++dx)
                #pragma unroll
                for (int j = 0; j < 4; ++j) {
                    float kv = kw[j + dx + 1];   // spatial w4+j+dx-3
                    acc0[dx][j] = fmaf(q0a[j], kv, acc0[dx][j]);
                    acc1[dx][j] = fmaf(q1a[j], kv, acc1[dx][j]);
                }
        }
        // no trailing barrier: next chunk stores into the other buffer
    }

    // cross-csub reduce (lanes 0..15 <-> 16..31 <-> 32..47 <-> 48..63)
    #pragma unroll
    for (int dx = 0; dx < 7; ++dx)
        #pragma unroll
        for (int j = 0; j < 4; ++j) {
            acc0[dx][j] += __shfl_xor(acc0[dx][j], 16, 64);
            acc0[dx][j] += __shfl_xor(acc0[dx][j], 32, 64);
            acc1[dx][j] += __shfl_xor(acc1[dx][j], 16, 64);
            acc1[dx][j] += __shfl_xor(acc1[dx][j], 32, 64);
        }
    // write lg (b128), distributed: csub writes dx with (dx&3)==csub
    #pragma unroll
    for (int dx = 0; dx < 7; ++dx) {
        if ((dx & 3) == csub) {
            if (do0) *(float4*)&lg[0][s*7 + dx][w4] =
                make_float4(acc0[dx][0], acc0[dx][1], acc0[dx][2], acc0[dx][3]);
            if (do1) *(float4*)&lg[1][(s-1)*7 + dx][w4] =
                make_float4(acc1[dx][0], acc1[dx][1], acc1[dx][2], acc1[dx][3]);
        }
    }

    // prefetch v chunk 0 (wave s -> chunk channels {2s,2s+1}, all 8 rows)
    float vreg[16];
    {
        #pragma unroll
        for (int i = 0; i < 16; ++i) {
            int c  = 2*s + (i >> 3);
            int r  = i & 7;
            int hh = h0 - PAD + r;
            vreg[i] = ((unsigned)hh < (unsigned)HH_)
                      ? vp[(size_t)c*HWSZ + hh*WW_ + w] : 0.f;
        }
    }
    __syncthreads();

    // -------- Phase B: two softmaxes (OOB logits exactly 0, included) ------
    if (tid < 128) {
        const int r = tid >> 6, px = tid & 63;
        float tv[NP];
        float m = -1e30f;
        #pragma unroll
        for (int p = 0; p < NP; ++p) { tv[p] = lg[r][p][px]; m = fmaxf(m, tv[p]); }
        float d = 0.f;
        #pragma unroll
        for (int p = 0; p < NP; ++p) {
            float e = __expf(tv[p] - m);
            d += e;
            lg[r][p][px] = e;
        }
        dn[r][px] = 1.f / d;
    } else {
        // zero vT halo cols {0..3, 68..71} x 8r x 16 slots in BOTH C-buffers
        // (2048 floats over threads 128..511)
        int t = tid - 128;
        for (int i = t; i < 2048; i += 384) {
            int buf  = i >> 10;
            int rem1 = i & 1023;
            int r    = rem1 >> 7;
            int rem  = rem1 & 127;
            int colg = rem >> 4;
            int col  = (colg < 4) ? colg : (64 + colg);
            smem[buf*9792 + r*1224 + col*17 + (rem & 15)] = 0.f;
        }
    }
    __syncthreads();

    // -------- Phase C (double-buffered, 1 barrier/chunk) --------
    float a0[NP], a1[NP];
    const float sc0 = dn[0][w], sc1 = dn[1][w];
    #pragma unroll
    for (int p = 0; p < NP; ++p) a0[p] = lg[0][p][w] * sc0;
    #pragma unroll
    for (int p = 0; p < NP; ++p) a1[p] = lg[1][p][w] * sc1;

    for (int ck = 0; ck < 8; ++ck) {
        float* vb = smem + (ck & 1)*9792;       // vT[8][72][17]
        // store vreg -> vT[r][4+w][c]  (stride 17 across lanes: conflict-free)
        #pragma unroll
        for (int i = 0; i < 16; ++i) {
            int c = 2*s + (i >> 3);
            int r = i & 7;
            vb[r*1224 + (4 + w)*17 + c] = vreg[i];
        }
        __syncthreads();
        if (ck < 7) {
            int c0v = (ck + 1) << 4;
            #pragma unroll
            for (int i = 0; i < 16; ++i) {
                int c  = 2*s + (i >> 3);
                int r  = i & 7;
                int hh = h0 - PAD + r;
                vreg[i] = ((unsigned)hh < (unsigned)HH_)
                          ? vp[(size_t)(c0v + c)*HWSZ + hh*WW_ + w] : 0.f;
            }
        }
        float y0a = 0.f, y0b = 0.f, y1a = 0.f, y1b = 0.f;
        #pragma unroll
        for (int r = 0; r < 8; ++r) {
            const float* vbase = &vb[r*1224 + (1 + w)*17 + 2*s];
            #pragma unroll
            for (int dx = 0; dx < 7; ++dx) {
                float va = vbase[17*dx];       // channel 2s
                float vb2 = vbase[17*dx + 1];  // channel 2s+1 (ds_read2 pair)
                if (r < 7) {
                    float aw = a0[r*7 + dx];
                    y0a = fmaf(aw, va, y0a); y0b = fmaf(aw, vb2, y0b);
                }
                if (r >= 1) {
                    float aw = a1[(r-1)*7 + dx];
                    y1a = fmaf(aw, va, y1a); y1b = fmaf(aw, vb2, y1b);
                }
            }
        }
        float* op = out + (size_t)b*CHW + (size_t)(ck*16 + 2*s)*HWSZ
                        + (size_t)h0*WW_ + w;
        op[0]          = y0a;   // c=2s,   row h0
        op[WW_]        = y1a;   // c=2s,   row h0+1
        op[HWSZ]       = y0b;   // c=2s+1, row h0
        op[HWSZ + WW_] = y1b;   // c=2s+1, row h0+1
        // no trailing barrier: next chunk stores into the other buffer
    }
}

extern "C" void kernel_launch(void* const* d_in, const int* in_sizes, int n_in,
                              void* d_out, int out_size, void* d_ws, size_t ws_size,
                              hipStream_t stream) {
    const float* x  = (const float*)d_in[0];
    const float* Wq = (const float*)d_in[1];
    const float* bq = (const float*)d_in[2];
    const float* Wk = (const float*)d_in[3];
    const float* bk = (const float*)d_in[4];
    const float* Wv = (const float*)d_in[5];
    const float* bv = (const float*)d_in[6];
    float* out = (float*)d_out;
    float* qkv = (float*)d_ws;   // 3*BCHW*4 = 50.3 MB scratch

    // d_out doubles as scratch for bf16 W (196 KB); fully overwritten by
    // locatt afterwards (stream-ordered), safe under re-poisoning.
    unsigned short* whi = (unsigned short*)d_out;
    unsigned short* wlo = whi + 3*16384;

    prep_w  <<<192, 256, 0, stream>>>(Wq, Wk, Wv, whi, wlo);
    qkv_mfma<<<dim3(256, 3), 256, 0, stream>>>(x, whi, wlo, bq, bk, bv, qkv);
    locatt  <<<256, 512, 0, stream>>>(qkv, out);
}